// Round 5
// baseline (217.414 us; speedup 1.0000x reference)
//
#include <hip/hip_runtime.h>

// SoftPool 2d: x(32,128,128,64) fp32, 2x2/stride2 windows.
// Per pixel: h = tanh(x @ We + be)  (64->128), logit = sigmoid(h @ Wr + br).
// Per window: softmax over 4 logits, out = sum_e w_e * x_e  (fp32 blend).
// One wave = 16 pixels = 4 windows; mfma_f32_16x16x32_bf16, N=128 (8 tiles), K=64 (2 steps).
// R5: concurrency restructure. R4 counters: VALU 26%/MFMA 4%/HBM 17%/Occ 20%
//     -> latency-starved, plus 1024 LDS-conflict-cycles of per-block transpose
//     prologue. Fix: prep kernel emits B-fragments in lane order to d_ws
//     (16KB, L2-hot); main kernel has NO LDS / NO syncthreads / L_=1 and
//     grid 8192 blocks (32 blocks/CU queued) -> block-level pipelining.

typedef __attribute__((ext_vector_type(8))) short short8;    // 8 bf16 = 4 VGPRs
typedef __attribute__((ext_vector_type(4))) float floatx4;

#define B_   32
#define R_   128
#define C_   128
#define D_   64
#define H_   128
#define NW_  (B_ * 64 * 64)     // 131072 windows
#define NGRP_ (NW_ / 4)         // 32768 groups of 4 windows (one per wave)
#define NBLK_ (NGRP_ / 4)       // 8192 blocks, 4 waves each, L_=1

#define L2E_  1.4426950408889634f   // log2(e)
#define T2L_  2.8853900817779268f   // 2*log2(e)

__device__ __forceinline__ unsigned short f2bf_rne(float f) {
  union { float f; unsigned int u; } v; v.f = f;
  unsigned int u = v.u;
  u += 0x7fffu + ((u >> 16) & 1u);
  return (unsigned short)(u >> 16);
}

// pack 2 floats -> 2 bf16 via v_perm (round-half-up), 3 VALU ops (verified R4)
__device__ __forceinline__ unsigned int pk_bf16(float lo, float hi) {
  unsigned int a = __builtin_bit_cast(unsigned int, lo) + 0x8000u;
  unsigned int b = __builtin_bit_cast(unsigned int, hi) + 0x8000u;
  return __builtin_amdgcn_perm(b, a, 0x07060302u);
}

// x += value from lane (lane ^ mask) within the 16-lane DPP row, VALU-rate.
template <int CTRL>
__device__ __forceinline__ float dpp_add(float x) {
  int xi = __builtin_bit_cast(int, x);
  int yi = __builtin_amdgcn_update_dpp(0, xi, CTRL, 0xf, 0xf, true);
  return x + __builtin_bit_cast(float, yi);
}
#define DPP_XOR1   0xB1    // quad_perm [1,0,3,2]
#define DPP_XOR3   0x1B    // quad_perm [3,2,1,0]
#define DPP_XOR7   0x141   // row_half_mirror
#define DPP_XOR15  0x140   // row_mirror
// masks {1,3,7,15} linearly independent over GF(2)^4 -> full 16-lane sum
__device__ __forceinline__ float row_reduce16(float x) {
  x = dpp_add<DPP_XOR1>(x);
  x = dpp_add<DPP_XOR3>(x);
  x = dpp_add<DPP_XOR7>(x);
  x = dpp_add<DPP_XOR15>(x);
  return x;
}

// ---- prep: B-fragments in per-lane order into d_ws ----
// F[fi=n*2+ks][lane=quad*16+c][j=0..7] = bf16( We[(ks*32+quad*8+j)*128 + n*16+c] )
// (identical values to the R1-verified LDS path: Bf[n][ks][j] = We[k][h],
//  k = ks*32+quad*8+j, h = n*16+c)
__global__ void prep_kernel(const float* __restrict__ We,
                            unsigned short* __restrict__ F)
{
  int t = blockIdx.x * 256 + threadIdx.x;   // 8192 threads, one element each
  int j    = t & 7;
  int lane = (t >> 3) & 63;
  int fi   = t >> 9;
  int n  = fi >> 1, ks = fi & 1;
  int quad = lane >> 4, c = lane & 15;
  F[t] = f2bf_rne(We[(ks * 32 + quad * 8 + j) * 128 + n * 16 + c]);
}

__global__ __launch_bounds__(256, 2) void softpool_kernel(
    const float* __restrict__ x, const unsigned short* __restrict__ F,
    const float* __restrict__ be, const float* __restrict__ Wr,
    const float* __restrict__ br, float* __restrict__ out)
{
  const int lane = threadIdx.x & 63;
  const int wv   = threadIdx.x >> 6;
  const int c    = lane & 15;   // A row (pixel-in-tile) / C col / out channel group
  const int quad = lane >> 4;   // k-quad for A/B; window-in-group for C/out

  const int g = blockIdx.x * 4 + wv;       // this wave's group of 4 windows

  // ---- issue ALL independent loads up front: 16 Bf + 8 data + 17 epi ----
  // B fragments: lane-contiguous 16B loads (1KiB per instruction), L2-hot.
  short8 Bf[8][2];
#pragma unroll
  for (int n = 0; n < 8; ++n)
#pragma unroll
    for (int ks = 0; ks < 2; ++ks)
      Bf[n][ks] = *(const short8*)&F[((n * 2 + ks) * 64 + lane) * 8];

  // A-frag pixel: p = c of the 16-pixel tile, channels quad*8..+7 (+32)
  const int w0   = g * 4 + (c >> 2);       // window of pixel p=c
  const int elem = c & 3;                  // elem = si*2+sj
  const int bb = w0 >> 12;
  const int qq = (w0 >> 6) & 63;
  const int pp = w0 & 63;
  const float* xp = x + (((bb * R_ + (qq * 2 + (elem >> 1))) * C_
                          + (pp * 2 + (elem & 1))) * D_) + quad * 8;
  floatx4 a0 = *(const floatx4*)(xp);
  floatx4 a1 = *(const floatx4*)(xp + 4);
  floatx4 a2 = *(const floatx4*)(xp + 32);
  floatx4 a3 = *(const floatx4*)(xp + 36);

  // blend window for this lane: wq = g*4 + quad, channels c*4..c*4+3
  const int wq = g * 4 + quad;
  const int b2 = wq >> 12;
  const int q2 = (wq >> 6) & 63;
  const int p2i = wq & 63;
  const float* xw = x + (((b2 * R_ + q2 * 2) * C_ + p2i * 2) * D_) + c * 4;
  floatx4 x0 = *(const floatx4*)(xw);
  floatx4 x1 = *(const floatx4*)(xw + D_);
  floatx4 x2 = *(const floatx4*)(xw + C_ * D_);
  floatx4 x3 = *(const floatx4*)(xw + C_ * D_ + D_);

  // epilogue constants: beK = be*2log2(e), wr2 = -2*Wr, swr = sum_n Wr
  float beK[8], wr2[8], swr = 0.f;
#pragma unroll
  for (int n = 0; n < 8; ++n) {
    float w = Wr[n * 16 + c];
    beK[n] = be[n * 16 + c] * T2L_;
    wr2[n] = -2.0f * w;
    swr += w;
  }
  const float brN = -L2E_ * br[0];

  // ---- bf16 A fragments (perm-packed converts) ----
  union { unsigned int u[4]; short8 v; } A0u, A1u;
  A0u.u[0] = pk_bf16(a0[0], a0[1]); A0u.u[1] = pk_bf16(a0[2], a0[3]);
  A0u.u[2] = pk_bf16(a1[0], a1[1]); A0u.u[3] = pk_bf16(a1[2], a1[3]);
  A1u.u[0] = pk_bf16(a2[0], a2[1]); A1u.u[1] = pk_bf16(a2[2], a2[3]);
  A1u.u[2] = pk_bf16(a3[0], a3[1]); A1u.u[3] = pk_bf16(a3[2], a3[3]);

  // ---- 16 MFMAs: h for 16 pixels x 128 hidden ----
  floatx4 acc[8];
#pragma unroll
  for (int n = 0; n < 8; ++n) {
    floatx4 z = {0.f, 0.f, 0.f, 0.f};
    z = __builtin_amdgcn_mfma_f32_16x16x32_bf16(A0u.v, Bf[n][0], z, 0, 0, 0);
    acc[n] = __builtin_amdgcn_mfma_f32_16x16x32_bf16(A1u.v, Bf[n][1], z, 0, 0, 0);
  }

  // ---- tanh-dot, rcp form: p = swr + sum_n (-2wr_n)*rcp(1+exp2(2L*(acc+be))) ----
  float p0 = swr, p1 = swr, p2 = swr, p3 = swr;
#pragma unroll
  for (int n = 0; n < 8; ++n) {
    float e0 = __builtin_amdgcn_exp2f(fmaf(acc[n][0], T2L_, beK[n]));
    float e1 = __builtin_amdgcn_exp2f(fmaf(acc[n][1], T2L_, beK[n]));
    float e2 = __builtin_amdgcn_exp2f(fmaf(acc[n][2], T2L_, beK[n]));
    float e3 = __builtin_amdgcn_exp2f(fmaf(acc[n][3], T2L_, beK[n]));
    p0 = fmaf(wr2[n], __builtin_amdgcn_rcpf(e0 + 1.0f), p0);
    p1 = fmaf(wr2[n], __builtin_amdgcn_rcpf(e1 + 1.0f), p1);
    p2 = fmaf(wr2[n], __builtin_amdgcn_rcpf(e2 + 1.0f), p2);
    p3 = fmaf(wr2[n], __builtin_amdgcn_rcpf(e3 + 1.0f), p3);
  }
  // reduce over the 16 lanes of this quad's DPP row (cols c=0..15), VALU-rate
  p0 = row_reduce16(p0);
  p1 = row_reduce16(p1);
  p2 = row_reduce16(p2);
  p3 = row_reduce16(p3);
  // sigmoid (rcp form); logits bounded [0,1] so softmax needs no max-subtract
  float l0 = __builtin_amdgcn_rcpf(1.0f + __builtin_amdgcn_exp2f(fmaf(p0, -L2E_, brN)));
  float l1 = __builtin_amdgcn_rcpf(1.0f + __builtin_amdgcn_exp2f(fmaf(p1, -L2E_, brN)));
  float l2 = __builtin_amdgcn_rcpf(1.0f + __builtin_amdgcn_exp2f(fmaf(p2, -L2E_, brN)));
  float l3 = __builtin_amdgcn_rcpf(1.0f + __builtin_amdgcn_exp2f(fmaf(p3, -L2E_, brN)));
  float s0 = __builtin_amdgcn_exp2f(l0 * L2E_);
  float s1 = __builtin_amdgcn_exp2f(l1 * L2E_);
  float s2 = __builtin_amdgcn_exp2f(l2 * L2E_);
  float s3 = __builtin_amdgcn_exp2f(l3 * L2E_);
  float inv = __builtin_amdgcn_rcpf(s0 + s1 + s2 + s3);
  float w0f = s0 * inv, w1f = s1 * inv, w2f = s2 * inv, w3f = s3 * inv;

  // ---- fp32 blend + store (wave writes 1KiB contiguous) ----
  floatx4 o = x0 * w0f + x1 * w1f + x2 * w2f + x3 * w3f;
  *(floatx4*)(out + (long)wq * 64 + c * 4) = o;
}

extern "C" void kernel_launch(void* const* d_in, const int* in_sizes, int n_in,
                              void* d_out, int out_size, void* d_ws, size_t ws_size,
                              hipStream_t stream) {
  const float* x  = (const float*)d_in[0];
  const float* We = (const float*)d_in[1];
  const float* be = (const float*)d_in[2];
  const float* Wr = (const float*)d_in[3];
  const float* br = (const float*)d_in[4];
  float* out = (float*)d_out;
  unsigned short* F = (unsigned short*)d_ws;   // 16 KB of fragment data

  prep_kernel<<<32, 256, 0, stream>>>(We, F);
  softpool_kernel<<<NBLK_, 256, 0, stream>>>(x, F, be, Wr, br, out);
}

// Round 6
// 210.013 us; speedup vs baseline: 1.0352x; 1.0352x over previous
//
#include <hip/hip_runtime.h>

// SoftPool 2d: x(32,128,128,64) fp32, 2x2/stride2 windows.
// Per pixel: h = tanh(x @ We + be)  (64->128), logit = sigmoid(h @ Wr + br).
// Per window: softmax over 4 logits, out = sum_e w_e * x_e  (fp32 blend).
// One wave = 16 pixels = 4 windows; mfma_f32_16x16x32_bf16, N=128 (8 tiles), K=64 (2 steps).
// R6: exact-resident grid. 1024 blocks (= 4 blocks/CU resident at VGPR~104,
//     no dispatch churn), L_=8 iters/wave with constant-stride advance
//     (+4 images/iter), no LDS / no syncthreads (Bf + epilogue constants
//     loaded once per wave from d_ws prep, amortized over 8 iters),
//     depth-1 cross-iter prefetch (R4). launch_bounds(256,2) — (256,4)
//     proven to spill (R2).

typedef __attribute__((ext_vector_type(8))) short short8;    // 8 bf16 = 4 VGPRs
typedef __attribute__((ext_vector_type(4))) float floatx4;

#define B_   32
#define R_   128
#define C_   128
#define D_   64
#define H_   128
#define NW_  (B_ * 64 * 64)     // 131072 windows
#define NGRP_ (NW_ / 4)         // 32768 groups of 4 windows
#define NBLK_ 1024              // 4 blocks/CU -> all resident, zero churn
#define NWAVE_ (NBLK_ * 4)      // 4096 waves
#define L_   (NGRP_ / NWAVE_)   // 8 iters per wave

#define XSTEP_ (4L * R_ * C_ * D_)       // +4 images per iter (in floats)
#define OSTEP_ ((long)NWAVE_ * 4 * 64)   // +16384 windows * 64 ch per iter

#define L2E_  1.4426950408889634f   // log2(e)
#define T2L_  2.8853900817779268f   // 2*log2(e)

__device__ __forceinline__ unsigned short f2bf_rne(float f) {
  union { float f; unsigned int u; } v; v.f = f;
  unsigned int u = v.u;
  u += 0x7fffu + ((u >> 16) & 1u);
  return (unsigned short)(u >> 16);
}

// pack 2 floats -> 2 bf16 via v_perm (round-half-up), 3 VALU ops (verified R4)
__device__ __forceinline__ unsigned int pk_bf16(float lo, float hi) {
  unsigned int a = __builtin_bit_cast(unsigned int, lo) + 0x8000u;
  unsigned int b = __builtin_bit_cast(unsigned int, hi) + 0x8000u;
  return __builtin_amdgcn_perm(b, a, 0x07060302u);
}

// x += value from lane (lane ^ mask) within the 16-lane DPP row, VALU-rate.
template <int CTRL>
__device__ __forceinline__ float dpp_add(float x) {
  int xi = __builtin_bit_cast(int, x);
  int yi = __builtin_amdgcn_update_dpp(0, xi, CTRL, 0xf, 0xf, true);
  return x + __builtin_bit_cast(float, yi);
}
#define DPP_XOR1   0xB1    // quad_perm [1,0,3,2]
#define DPP_XOR3   0x1B    // quad_perm [3,2,1,0]
#define DPP_XOR7   0x141   // row_half_mirror
#define DPP_XOR15  0x140   // row_mirror
// masks {1,3,7,15} linearly independent over GF(2)^4 -> full 16-lane sum
__device__ __forceinline__ float row_reduce16(float x) {
  x = dpp_add<DPP_XOR1>(x);
  x = dpp_add<DPP_XOR3>(x);
  x = dpp_add<DPP_XOR7>(x);
  x = dpp_add<DPP_XOR15>(x);
  return x;
}

// ---- prep: B-fragments in per-lane order into d_ws (verified R5) ----
// F[fi=n*2+ks][lane=quad*16+c][j=0..7] = bf16( We[(ks*32+quad*8+j)*128 + n*16+c] )
__global__ void prep_kernel(const float* __restrict__ We,
                            unsigned short* __restrict__ F)
{
  int t = blockIdx.x * 256 + threadIdx.x;   // 8192 threads, one element each
  int j    = t & 7;
  int lane = (t >> 3) & 63;
  int fi   = t >> 9;
  int n  = fi >> 1, ks = fi & 1;
  int quad = lane >> 4, c = lane & 15;
  F[t] = f2bf_rne(We[(ks * 32 + quad * 8 + j) * 128 + n * 16 + c]);
}

__global__ __launch_bounds__(256, 2) void softpool_kernel(
    const float* __restrict__ x, const unsigned short* __restrict__ F,
    const float* __restrict__ be, const float* __restrict__ Wr,
    const float* __restrict__ br, float* __restrict__ out)
{
  const int lane = threadIdx.x & 63;
  const int wv   = threadIdx.x >> 6;
  const int c    = lane & 15;   // A row (pixel-in-tile) / C col / out channel group
  const int quad = lane >> 4;   // k-quad for A/B; window-in-group for C/out

  // ---- once-per-wave setup, amortized over L_=8 iters ----
  // B fragments: lane-contiguous 16B loads (1KiB/instr), L2-hot.
  short8 Bf[8][2];
#pragma unroll
  for (int n = 0; n < 8; ++n)
#pragma unroll
    for (int ks = 0; ks < 2; ++ks)
      Bf[n][ks] = *(const short8*)&F[((n * 2 + ks) * 64 + lane) * 8];

  // epilogue constants: beK = be*2log2(e), wr2 = -2*Wr, swr = sum_n Wr
  float beK[8], wr2[8], swr = 0.f;
#pragma unroll
  for (int n = 0; n < 8; ++n) {
    float w = Wr[n * 16 + c];
    beK[n] = be[n * 16 + c] * T2L_;
    wr2[n] = -2.0f * w;
    swr += w;
  }
  const float brN = -L2E_ * br[0];

  const int gw = blockIdx.x * 4 + wv;     // iter-0 group; g advances by +4096/iter

  // ---- iter-0 addresses (thereafter: +4 images exactly per iter) ----
  const int w0   = gw * 4 + (c >> 2);     // window of pixel p=c
  const int elem = c & 3;                 // elem = si*2+sj
  const int bb = w0 >> 12;
  const int qq = (w0 >> 6) & 63;
  const int pp = w0 & 63;
  const float* xp = x + (((bb * R_ + (qq * 2 + (elem >> 1))) * C_
                          + (pp * 2 + (elem & 1))) * D_) + quad * 8;

  const int wq0 = gw * 4 + quad;          // this lane's blend window, iter 0
  const int b2 = wq0 >> 12;
  const int q2 = (wq0 >> 6) & 63;
  const int p2i = wq0 & 63;
  const float* xw = x + (((b2 * R_ + q2 * 2) * C_ + p2i * 2) * D_) + c * 4;
  float* op = out + (long)wq0 * 64 + c * 4;

  // ---- preload iter 0 ----
  floatx4 a0 = *(const floatx4*)(xp);
  floatx4 a1 = *(const floatx4*)(xp + 4);
  floatx4 a2 = *(const floatx4*)(xp + 32);
  floatx4 a3 = *(const floatx4*)(xp + 36);
  floatx4 x0 = *(const floatx4*)(xw);
  floatx4 x1 = *(const floatx4*)(xw + D_);
  floatx4 x2 = *(const floatx4*)(xw + C_ * D_);
  floatx4 x3 = *(const floatx4*)(xw + C_ * D_ + D_);

  for (int it = 0; it < L_; ++it) {
    // ---- prefetch next iter (redundant same-addr reload on last iter) ----
    const long nd = (it < L_ - 1) ? XSTEP_ : 0;
    const float* xpn = xp + nd;
    const float* xwn = xw + nd;
    floatx4 na0 = *(const floatx4*)(xpn);
    floatx4 na1 = *(const floatx4*)(xpn + 4);
    floatx4 na2 = *(const floatx4*)(xpn + 32);
    floatx4 na3 = *(const floatx4*)(xpn + 36);
    floatx4 nx0 = *(const floatx4*)(xwn);
    floatx4 nx1 = *(const floatx4*)(xwn + D_);
    floatx4 nx2 = *(const floatx4*)(xwn + C_ * D_);
    floatx4 nx3 = *(const floatx4*)(xwn + C_ * D_ + D_);

    // ---- bf16 A fragments (perm-packed converts) ----
    union { unsigned int u[4]; short8 v; } A0u, A1u;
    A0u.u[0] = pk_bf16(a0[0], a0[1]); A0u.u[1] = pk_bf16(a0[2], a0[3]);
    A0u.u[2] = pk_bf16(a1[0], a1[1]); A0u.u[3] = pk_bf16(a1[2], a1[3]);
    A1u.u[0] = pk_bf16(a2[0], a2[1]); A1u.u[1] = pk_bf16(a2[2], a2[3]);
    A1u.u[2] = pk_bf16(a3[0], a3[1]); A1u.u[3] = pk_bf16(a3[2], a3[3]);

    // ---- 16 MFMAs: h for 16 pixels x 128 hidden ----
    floatx4 acc[8];
#pragma unroll
    for (int n = 0; n < 8; ++n) {
      floatx4 z = {0.f, 0.f, 0.f, 0.f};
      z = __builtin_amdgcn_mfma_f32_16x16x32_bf16(A0u.v, Bf[n][0], z, 0, 0, 0);
      acc[n] = __builtin_amdgcn_mfma_f32_16x16x32_bf16(A1u.v, Bf[n][1], z, 0, 0, 0);
    }

    // ---- tanh-dot, rcp form: p = swr + sum_n (-2wr_n)*rcp(1+exp2(2L*(acc+be))) ----
    float p0 = swr, p1 = swr, p2 = swr, p3 = swr;
#pragma unroll
    for (int n = 0; n < 8; ++n) {
      float e0 = __builtin_amdgcn_exp2f(fmaf(acc[n][0], T2L_, beK[n]));
      float e1 = __builtin_amdgcn_exp2f(fmaf(acc[n][1], T2L_, beK[n]));
      float e2 = __builtin_amdgcn_exp2f(fmaf(acc[n][2], T2L_, beK[n]));
      float e3 = __builtin_amdgcn_exp2f(fmaf(acc[n][3], T2L_, beK[n]));
      p0 = fmaf(wr2[n], __builtin_amdgcn_rcpf(e0 + 1.0f), p0);
      p1 = fmaf(wr2[n], __builtin_amdgcn_rcpf(e1 + 1.0f), p1);
      p2 = fmaf(wr2[n], __builtin_amdgcn_rcpf(e2 + 1.0f), p2);
      p3 = fmaf(wr2[n], __builtin_amdgcn_rcpf(e3 + 1.0f), p3);
    }
    // reduce over the 16 lanes of this quad's DPP row (cols c=0..15), VALU-rate
    p0 = row_reduce16(p0);
    p1 = row_reduce16(p1);
    p2 = row_reduce16(p2);
    p3 = row_reduce16(p3);
    // sigmoid (rcp form); logits bounded [0,1] so softmax needs no max-subtract
    float l0 = __builtin_amdgcn_rcpf(1.0f + __builtin_amdgcn_exp2f(fmaf(p0, -L2E_, brN)));
    float l1 = __builtin_amdgcn_rcpf(1.0f + __builtin_amdgcn_exp2f(fmaf(p1, -L2E_, brN)));
    float l2 = __builtin_amdgcn_rcpf(1.0f + __builtin_amdgcn_exp2f(fmaf(p2, -L2E_, brN)));
    float l3 = __builtin_amdgcn_rcpf(1.0f + __builtin_amdgcn_exp2f(fmaf(p3, -L2E_, brN)));
    float s0 = __builtin_amdgcn_exp2f(l0 * L2E_);
    float s1 = __builtin_amdgcn_exp2f(l1 * L2E_);
    float s2 = __builtin_amdgcn_exp2f(l2 * L2E_);
    float s3 = __builtin_amdgcn_exp2f(l3 * L2E_);
    float inv = __builtin_amdgcn_rcpf(s0 + s1 + s2 + s3);
    float w0f = s0 * inv, w1f = s1 * inv, w2f = s2 * inv, w3f = s3 * inv;

    // ---- fp32 blend + store (wave writes 1KiB contiguous) ----
    floatx4 o = x0 * w0f + x1 * w1f + x2 * w2f + x3 * w3f;
    *(floatx4*)(op) = o;

    // ---- rotate pipeline ----
    xp = xpn; xw = xwn; op += OSTEP_;
    a0 = na0; a1 = na1; a2 = na2; a3 = na3;
    x0 = nx0; x1 = nx1; x2 = nx2; x3 = nx3;
  }
}

extern "C" void kernel_launch(void* const* d_in, const int* in_sizes, int n_in,
                              void* d_out, int out_size, void* d_ws, size_t ws_size,
                              hipStream_t stream) {
  const float* x  = (const float*)d_in[0];
  const float* We = (const float*)d_in[1];
  const float* be = (const float*)d_in[2];
  const float* Wr = (const float*)d_in[3];
  const float* br = (const float*)d_in[4];
  float* out = (float*)d_out;
  unsigned short* F = (unsigned short*)d_ws;   // 16 KB of fragment data

  prep_kernel<<<32, 256, 0, stream>>>(We, F);
  softpool_kernel<<<NBLK_, 256, 0, stream>>>(x, F, be, Wr, br, out);
}